// Round 1
// baseline (1184.312 us; speedup 1.0000x reference)
//
#include <hip/hip_runtime.h>
#include <hip/hip_bf16.h>
#include <math.h>

// Problem constants
#define NPTS 8192
#define BDIM 4
#define BN   32768   // BDIM*NPTS
#define CDIM 256
#define KNN  16
#define NNCOL 32

// ---------------------------------------------------------------------------
// Row stats for LayerNorm: mean + rstd per row of a [rows][256] fp32 matrix.
// One wave per row, 4 rows per block.
// ---------------------------------------------------------------------------
__global__ __launch_bounds__(256) void stats_kernel(const float* __restrict__ x,
                                                    float* __restrict__ st) {
  int row = blockIdx.x * 4 + (threadIdx.x >> 6);
  int l = threadIdx.x & 63;
  const float4 v = *(const float4*)(x + (size_t)row * CDIM + l * 4);
  float s  = v.x + v.y + v.z + v.w;
  float sq = v.x * v.x + v.y * v.y + v.z * v.z + v.w * v.w;
  #pragma unroll
  for (int off = 1; off < 64; off <<= 1) {
    s  += __shfl_xor(s, off);
    sq += __shfl_xor(sq, off);
  }
  if (l == 0) {
    float m   = s * (1.0f / 256.0f);
    float var = sq * (1.0f / 256.0f) - m * m;
    st[row * 2 + 0] = m;
    st[row * 2 + 1] = rsqrtf(var + 1e-5f);
  }
}

// ---------------------------------------------------------------------------
// Tiled fp32 GEMM: C[m,n] = op( A'[m,:] @ B[:,n] + bias[n] (+ res) )
//   AMODE 0: A' = A
//   AMODE 1: A' = (A - mean[m]) * rstd[m] * g[k] + b[k]   (fused LayerNorm)
//   EPI 0: store acc
//   EPI 1: store acc + bias
//   EPI 2: store acc + bias + res
//   EPI 3: store gelu(acc + bias)        (exact erf gelu)
// Tile: 64x64, BK=32, 256 threads, 4x4 micro-tile.
// ---------------------------------------------------------------------------
__device__ __forceinline__ float gelu_exact(float z) {
  return 0.5f * z * (1.0f + erff(z * 0.70710678118654752f));
}

template <int AMODE, int EPI>
__global__ __launch_bounds__(256) void gemm_kernel(
    const float* __restrict__ A, const float* __restrict__ Bm,
    const float* __restrict__ bias, float* __restrict__ Cm,
    const float* __restrict__ res, int M, int Nn, int Kk,
    const float* __restrict__ st, const float* __restrict__ lng,
    const float* __restrict__ lnb) {
  __shared__ __align__(16) float As[32][68];  // [k][m], padded
  __shared__ __align__(16) float Bs[32][68];  // [k][n], padded

  const int t  = threadIdx.x;
  const int tx = t & 15;
  const int ty = t >> 4;
  const int m0 = blockIdx.y * 64;
  const int n0 = blockIdx.x * 64;

  // A-tile load mapping: rows am, am+32; k-quad ak
  const int am = t >> 3;        // 0..31
  const int ak = (t & 7) * 4;   // 0..28
  // B-tile load mapping: rows bk, bk+16; n-quad bn
  const int bk = t >> 4;        // 0..15
  const int bn = (t & 15) * 4;  // 0..60

  float acc[4][4] = {};

  float mean0 = 0.f, rstd0 = 0.f, mean1 = 0.f, rstd1 = 0.f;
  if (AMODE == 1) {
    mean0 = st[(m0 + am) * 2 + 0];
    rstd0 = st[(m0 + am) * 2 + 1];
    mean1 = st[(m0 + am + 32) * 2 + 0];
    rstd1 = st[(m0 + am + 32) * 2 + 1];
  }

  for (int k0 = 0; k0 < Kk; k0 += 32) {
    float4 a0 = *(const float4*)(A + (size_t)(m0 + am) * Kk + k0 + ak);
    float4 a1 = *(const float4*)(A + (size_t)(m0 + am + 32) * Kk + k0 + ak);
    if (AMODE == 1) {
      const float4 gv = *(const float4*)(lng + k0 + ak);
      const float4 bv = *(const float4*)(lnb + k0 + ak);
      a0.x = (a0.x - mean0) * rstd0 * gv.x + bv.x;
      a0.y = (a0.y - mean0) * rstd0 * gv.y + bv.y;
      a0.z = (a0.z - mean0) * rstd0 * gv.z + bv.z;
      a0.w = (a0.w - mean0) * rstd0 * gv.w + bv.w;
      a1.x = (a1.x - mean1) * rstd1 * gv.x + bv.x;
      a1.y = (a1.y - mean1) * rstd1 * gv.y + bv.y;
      a1.z = (a1.z - mean1) * rstd1 * gv.z + bv.z;
      a1.w = (a1.w - mean1) * rstd1 * gv.w + bv.w;
    }
    const float4 b0 = *(const float4*)(Bm + (size_t)(k0 + bk) * Nn + n0 + bn);
    const float4 b1 = *(const float4*)(Bm + (size_t)(k0 + bk + 16) * Nn + n0 + bn);

    As[ak + 0][am] = a0.x; As[ak + 1][am] = a0.y;
    As[ak + 2][am] = a0.z; As[ak + 3][am] = a0.w;
    As[ak + 0][am + 32] = a1.x; As[ak + 1][am + 32] = a1.y;
    As[ak + 2][am + 32] = a1.z; As[ak + 3][am + 32] = a1.w;
    *(float4*)&Bs[bk][bn]      = b0;
    *(float4*)&Bs[bk + 16][bn] = b1;
    __syncthreads();

    #pragma unroll 8
    for (int kk = 0; kk < 32; kk++) {
      const float4 a4 = *(const float4*)&As[kk][ty * 4];
      const float4 b4 = *(const float4*)&Bs[kk][tx * 4];
      const float ar[4] = {a4.x, a4.y, a4.z, a4.w};
      const float br[4] = {b4.x, b4.y, b4.z, b4.w};
      #pragma unroll
      for (int i = 0; i < 4; i++)
        #pragma unroll
        for (int j = 0; j < 4; j++) acc[i][j] += ar[i] * br[j];
    }
    __syncthreads();
  }

  // Epilogue
  const int gn = n0 + tx * 4;
  float4 bv = {0.f, 0.f, 0.f, 0.f};
  if (EPI >= 1) bv = *(const float4*)(bias + gn);
  #pragma unroll
  for (int i = 0; i < 4; i++) {
    const int gm = m0 + ty * 4 + i;
    float4 o;
    o.x = acc[i][0] + bv.x;
    o.y = acc[i][1] + bv.y;
    o.z = acc[i][2] + bv.z;
    o.w = acc[i][3] + bv.w;
    if (EPI == 2) {
      const float4 r = *(const float4*)(res + (size_t)gm * Nn + gn);
      o.x += r.x; o.y += r.y; o.z += r.z; o.w += r.w;
    }
    if (EPI == 3) {
      o.x = gelu_exact(o.x); o.y = gelu_exact(o.y);
      o.z = gelu_exact(o.z); o.w = gelu_exact(o.w);
    }
    *(float4*)(Cm + (size_t)gm * Nn + gn) = o;
  }
}

// ---------------------------------------------------------------------------
// Fused attention: per point, gather K=16 neighbors, per-head softmax,
// weighted sums s[h][c] = sum_k a[h,k]*relu(u[k,c]) and ov[c] = sum_k a*v,
// then out[c] = ov[c] + b_d2[c] + sum_c' s[h(c)][c'] * w_d2[c'][c].
// Block = 256 threads (4 waves), 8 points (2 per wave).
// ---------------------------------------------------------------------------
__global__ __launch_bounds__(256) void attn_kernel(
    const float* __restrict__ qkv, const int* __restrict__ nns,
    const float* __restrict__ xyz, const float* __restrict__ w_d1,
    const float* __restrict__ b_d1, const float* __restrict__ w_d2,
    const float* __restrict__ b_d2, float* __restrict__ out) {
  __shared__ __align__(16) float s_lds[8][4][256];
  __shared__ __align__(16) float ov_lds[8][256];
  __shared__ float a_lds[8][64];

  const int t = threadIdx.x;
  const int w = t >> 6;   // wave id
  const int l = t & 63;   // lane
  const int h = l >> 4;   // head for this lane's channels
  const int c0 = l * 4;   // this lane's channel quad
  const int blk = blockIdx.x;

  // hoisted per-lane constants
  const float4 w10 = *(const float4*)(w_d1 + c0);
  const float4 w11 = *(const float4*)(w_d1 + 256 + c0);
  const float4 b1v = *(const float4*)(b_d1 + c0);
  const float4 b2v = *(const float4*)(b_d2 + c0);

  for (int pl = 0; pl < 2; pl++) {
    const int p  = w * 2 + pl;
    const int gp = blk * 8 + p;
    const int b  = gp >> 13;  // N = 8192

    const float4 q4 = *(const float4*)(qkv + (size_t)gp * 768 + c0);
    const float2 xy0 = *(const float2*)(xyz + gp * 2);

    int rowj[KNN];
    #pragma unroll
    for (int j = 0; j < KNN; j++) rowj[j] = (b << 13) + nns[gp * NNCOL + j];

    // scores: swapped layout — after reduction lane l holds score for
    // j = l&15 of head l>>4.
    float myscore = 0.f;
    #pragma unroll
    for (int j = 0; j < KNN; j++) {
      const float4 k4 = *(const float4*)(qkv + (size_t)rowj[j] * 768 + 256 + c0);
      float d = q4.x * k4.x + q4.y * k4.y + q4.z * k4.z + q4.w * k4.w;
      d += __shfl_xor(d, 1); d += __shfl_xor(d, 2);
      d += __shfl_xor(d, 4); d += __shfl_xor(d, 8);
      if ((l & 15) == j) myscore = d;
    }
    myscore *= 0.125f;  // 1/sqrt(64)

    // softmax across the 16-lane group (axis j)
    float mx = myscore;
    mx = fmaxf(mx, __shfl_xor(mx, 1)); mx = fmaxf(mx, __shfl_xor(mx, 2));
    mx = fmaxf(mx, __shfl_xor(mx, 4)); mx = fmaxf(mx, __shfl_xor(mx, 8));
    float e = __expf(myscore - mx);
    float sum = e;
    sum += __shfl_xor(sum, 1); sum += __shfl_xor(sum, 2);
    sum += __shfl_xor(sum, 4); sum += __shfl_xor(sum, 8);
    const float a = e / sum;
    a_lds[p][l] = a;  // l = h*16 + j
    __syncthreads();

    float sacc[4][4] = {};
    float4 ov = {0.f, 0.f, 0.f, 0.f};
    #pragma unroll
    for (int j = 0; j < KNN; j++) {
      const int r = rowj[j];
      const float4 v4 = *(const float4*)(qkv + (size_t)r * 768 + 512 + c0);
      const float2 xyj = *(const float2*)(xyz + r * 2);
      const float rx = xy0.x - xyj.x;
      const float ry = xy0.y - xyj.y;
      const float u0 = fmaxf(rx * w10.x + ry * w11.x + b1v.x, 0.f);
      const float u1 = fmaxf(rx * w10.y + ry * w11.y + b1v.y, 0.f);
      const float u2 = fmaxf(rx * w10.z + ry * w11.z + b1v.z, 0.f);
      const float u3 = fmaxf(rx * w10.w + ry * w11.w + b1v.w, 0.f);
      const float a0 = a_lds[p][0 * 16 + j];
      const float a1 = a_lds[p][1 * 16 + j];
      const float a2 = a_lds[p][2 * 16 + j];
      const float a3 = a_lds[p][3 * 16 + j];
      sacc[0][0] += a0 * u0; sacc[0][1] += a0 * u1; sacc[0][2] += a0 * u2; sacc[0][3] += a0 * u3;
      sacc[1][0] += a1 * u0; sacc[1][1] += a1 * u1; sacc[1][2] += a1 * u2; sacc[1][3] += a1 * u3;
      sacc[2][0] += a2 * u0; sacc[2][1] += a2 * u1; sacc[2][2] += a2 * u2; sacc[2][3] += a2 * u3;
      sacc[3][0] += a3 * u0; sacc[3][1] += a3 * u1; sacc[3][2] += a3 * u2; sacc[3][3] += a3 * u3;
      const float aown = (h < 2) ? (h == 0 ? a0 : a1) : (h == 2 ? a2 : a3);
      ov.x += aown * v4.x; ov.y += aown * v4.y;
      ov.z += aown * v4.z; ov.w += aown * v4.w;
    }
    #pragma unroll
    for (int hh = 0; hh < 4; hh++) {
      float4 sv;
      sv.x = sacc[hh][0]; sv.y = sacc[hh][1];
      sv.z = sacc[hh][2]; sv.w = sacc[hh][3];
      *(float4*)&s_lds[p][hh][c0] = sv;
    }
    float4 ovw;
    ovw.x = ov.x + b2v.x; ovw.y = ov.y + b2v.y;
    ovw.z = ov.z + b2v.z; ovw.w = ov.w + b2v.w;
    *(float4*)&ov_lds[p][c0] = ovw;
  }
  __syncthreads();

  // Phase 2: out[p][d] = ov[p][d] + sum_c s[p][h(d)][c] * w_d2[c][d]
  const int d  = t;        // 0..255
  const int hh = d >> 6;   // == wave id, wave-uniform
  float acc2[8];
  #pragma unroll
  for (int p = 0; p < 8; p++) acc2[p] = ov_lds[p][d];

  for (int c = 0; c < 256; c += 4) {
    const float wv0 = w_d2[(c + 0) * 256 + d];
    const float wv1 = w_d2[(c + 1) * 256 + d];
    const float wv2 = w_d2[(c + 2) * 256 + d];
    const float wv3 = w_d2[(c + 3) * 256 + d];
    #pragma unroll
    for (int p = 0; p < 8; p++) {
      const float4 s4 = *(const float4*)&s_lds[p][hh][c];
      acc2[p] += s4.x * wv0 + s4.y * wv1 + s4.z * wv2 + s4.w * wv3;
    }
  }
  const int gp0 = blk * 8;
  #pragma unroll
  for (int p = 0; p < 8; p++) out[(size_t)(gp0 + p) * 256 + d] = acc2[p];
}

// ---------------------------------------------------------------------------
// Launch
// ---------------------------------------------------------------------------
extern "C" void kernel_launch(void* const* d_in, const int* in_sizes, int n_in,
                              void* d_out, int out_size, void* d_ws,
                              size_t ws_size, hipStream_t stream) {
  const float* xyz      = (const float*)d_in[0];
  const float* xy_embed = (const float*)d_in[1];
  const int*   nns      = (const int*)d_in[2];
  const float* ln1_g    = (const float*)d_in[3];
  const float* ln1_b    = (const float*)d_in[4];
  const float* w_qkv    = (const float*)d_in[5];
  const float* w_d1     = (const float*)d_in[6];
  const float* b_d1     = (const float*)d_in[7];
  const float* w_d2     = (const float*)d_in[8];
  const float* b_d2     = (const float*)d_in[9];
  const float* w_proj   = (const float*)d_in[10];
  const float* b_proj   = (const float*)d_in[11];
  const float* ln2_g    = (const float*)d_in[12];
  const float* ln2_b    = (const float*)d_in[13];
  const float* w_m1     = (const float*)d_in[14];
  const float* b_m1     = (const float*)d_in[15];
  const float* w_m2     = (const float*)d_in[16];
  const float* b_m2     = (const float*)d_in[17];
  float* out = (float*)d_out;

  char* ws = (char*)d_ws;
  float* qkv     = (float*)ws;                              // BN*768*4  = 96 MB
  float* attnout = (float*)(ws + (size_t)BN * 768 * 4);     // BN*256*4  = 32 MB
  float* mid     = attnout;                                 // reused after proj
  float* st1     = (float*)(ws + (size_t)BN * 768 * 4 + (size_t)BN * 256 * 4);
  float* st2     = st1 + BN * 2;

  // 1. LN1 stats
  stats_kernel<<<BN / 4, 256, 0, stream>>>(xy_embed, st1);

  // 2. qkv = LN1(xy_embed) @ w_qkv
  gemm_kernel<1, 0><<<dim3(768 / 64, BN / 64), 256, 0, stream>>>(
      xy_embed, w_qkv, nullptr, qkv, nullptr, BN, 768, 256, st1, ln1_g, ln1_b);

  // 3. fused neighborhood attention (+pe restructure)
  attn_kernel<<<BN / 8, 256, 0, stream>>>(qkv, nns, xyz, w_d1, b_d1, w_d2,
                                          b_d2, attnout);

  // 4. x = xy_embed + attnout @ w_proj + b_proj   -> d_out
  gemm_kernel<0, 2><<<dim3(256 / 64, BN / 64), 256, 0, stream>>>(
      attnout, w_proj, b_proj, out, xy_embed, BN, 256, 256, nullptr, nullptr,
      nullptr);

  // 5. LN2 stats on x
  stats_kernel<<<BN / 4, 256, 0, stream>>>(out, st2);

  // 6/7. MLP, chunked over rows (mid reuses the attnout region, 32 MB)
  const int CHUNK = 8192;
  for (int ch = 0; ch < BN / CHUNK; ch++) {
    const float* xrow = out + (size_t)ch * CHUNK * 256;
    gemm_kernel<1, 3><<<dim3(1024 / 64, CHUNK / 64), 256, 0, stream>>>(
        xrow, w_m1, b_m1, mid, nullptr, CHUNK, 1024, 256,
        st2 + (size_t)ch * CHUNK * 2, ln2_g, ln2_b);
    gemm_kernel<0, 2><<<dim3(256 / 64, CHUNK / 64), 256, 0, stream>>>(
        mid, w_m2, b_m2, out + (size_t)ch * CHUNK * 256, xrow, CHUNK, 256,
        1024, nullptr, nullptr, nullptr);
  }
}

// Round 3
// 907.396 us; speedup vs baseline: 1.3052x; 1.3052x over previous
//
#include <hip/hip_runtime.h>
#include <hip/hip_bf16.h>
#include <math.h>

// Problem constants
#define NPTS 8192
#define BDIM 4
#define BN   32768   // BDIM*NPTS
#define CDIM 256
#define KNN  16
#define NNCOL 32

typedef __attribute__((ext_vector_type(8))) short short8_t;
typedef __attribute__((ext_vector_type(4))) float f32x4;

// ---------------------------------------------------------------------------
// Row stats for LayerNorm: mean + rstd per row of a [rows][256] fp32 matrix.
// ---------------------------------------------------------------------------
__global__ __launch_bounds__(256) void stats_kernel(const float* __restrict__ x,
                                                    float* __restrict__ st) {
  int row = blockIdx.x * 4 + (threadIdx.x >> 6);
  int l = threadIdx.x & 63;
  const float4 v = *(const float4*)(x + (size_t)row * CDIM + l * 4);
  float s  = v.x + v.y + v.z + v.w;
  float sq = v.x * v.x + v.y * v.y + v.z * v.z + v.w * v.w;
  #pragma unroll
  for (int off = 1; off < 64; off <<= 1) {
    s  += __shfl_xor(s, off);
    sq += __shfl_xor(sq, off);
  }
  if (l == 0) {
    float m   = s * (1.0f / 256.0f);
    float var = sq * (1.0f / 256.0f) - m * m;
    st[row * 2 + 0] = m;
    st[row * 2 + 1] = rsqrtf(var + 1e-5f);
  }
}

__device__ __forceinline__ float gelu_exact(float z) {
  return 0.5f * z * (1.0f + erff(z * 0.70710678118654752f));
}

// Split fp32 into bf16 hi (truncate) + bf16 lo (truncate of remainder).
__device__ __forceinline__ void bf16_split(float f, ushort& h, ushort& l) {
  unsigned int u = __float_as_uint(f);
  h = (ushort)(u >> 16);
  float fh = __uint_as_float(u & 0xffff0000u);
  float r = f - fh;
  l = (ushort)(__float_as_uint(r) >> 16);
}

// ---------------------------------------------------------------------------
// MFMA bf16x3 GEMM: C[m,n] = epi( A'[m,:] @ B[:,n] )
//   AMODE 0: A' = A;  AMODE 1: A' = LN(A) (fused via st/lng/lnb)
//   EPI 0: acc; 1: +bias; 2: +bias+res; 3: gelu(acc+bias)
// Tile 128x128, BK=32, 256 threads = 4 waves (2x2), each wave 64x64 via
// 4x4 fragments of v_mfma_f32_16x16x32_bf16.
// LDS = 4 x (128x32 ushort) = 32 KiB.
// Swizzle: ushort_off ^= (row&3)<<3  (byte ^= (row&3)<<4), write-granule 4
// ushorts and read-granule 8 ushorts both preserved.
// ---------------------------------------------------------------------------
template <int AMODE, int EPI>
__global__ __launch_bounds__(256) void gemm_mfma(
    const float* __restrict__ A, const float* __restrict__ Bm,
    const float* __restrict__ bias, float* __restrict__ Cm,
    const float* __restrict__ res, int M, int Nn, int Kk,
    const float* __restrict__ st, const float* __restrict__ lng,
    const float* __restrict__ lnb) {
  __shared__ __align__(16) ushort AsH[128 * 32];
  __shared__ __align__(16) ushort AsL[128 * 32];
  __shared__ __align__(16) ushort BsH[128 * 32];
  __shared__ __align__(16) ushort BsL[128 * 32];

  const int t = threadIdx.x;
  const int w = t >> 6;
  const int l = t & 63;
  const int la = l & 15;   // frag row/col lane
  const int lb = l >> 4;   // frag k-group / acc row group
  const int wr = w >> 1;   // wave row (0/1)
  const int wc = w & 1;    // wave col (0/1)
  const int m0 = blockIdx.y * 128;
  const int n0 = blockIdx.x * 128;

  // A staging map: thread handles rows mA+32*i (i=0..3), k-quad kqA
  const int mA  = t >> 3;       // 0..31
  const int kqA = (t & 7) * 4;  // 0..28
  // B staging map: thread handles k-quad kbB, n-quad nbB (transpose 4x4)
  const int kbB = (t >> 5) * 4; // 0..28
  const int nbB = (t & 31) * 4; // 0..124

  float means[4], rstds[4];
  if (AMODE == 1) {
    #pragma unroll
    for (int i = 0; i < 4; i++) {
      means[i] = st[(m0 + mA + 32 * i) * 2 + 0];
      rstds[i] = st[(m0 + mA + 32 * i) * 2 + 1];
    }
  }

  f32x4 acc[4][4];
  #pragma unroll
  for (int i = 0; i < 4; i++)
    #pragma unroll
    for (int j = 0; j < 4; j++) acc[i][j] = (f32x4){0.f, 0.f, 0.f, 0.f};

  for (int k0 = 0; k0 < Kk; k0 += 32) {
    // ---- stage A: 128 x 32 fp32 -> bf16 hi/lo, [m][k], swizzled
    float4 gv, bvv;
    if (AMODE == 1) {
      gv  = *(const float4*)(lng + k0 + kqA);
      bvv = *(const float4*)(lnb + k0 + kqA);
    }
    #pragma unroll
    for (int i = 0; i < 4; i++) {
      const int m = mA + 32 * i;
      float4 a = *(const float4*)(A + (size_t)(m0 + m) * Kk + k0 + kqA);
      if (AMODE == 1) {
        a.x = (a.x - means[i]) * rstds[i] * gv.x + bvv.x;
        a.y = (a.y - means[i]) * rstds[i] * gv.y + bvv.y;
        a.z = (a.z - means[i]) * rstds[i] * gv.z + bvv.z;
        a.w = (a.w - means[i]) * rstds[i] * gv.w + bvv.w;
      }
      ushort4 hv, lv;
      bf16_split(a.x, hv.x, lv.x); bf16_split(a.y, hv.y, lv.y);
      bf16_split(a.z, hv.z, lv.z); bf16_split(a.w, hv.w, lv.w);
      const int off = m * 32 + (kqA ^ ((m & 3) << 3));
      *(ushort4*)&AsH[off] = hv;
      *(ushort4*)&AsL[off] = lv;
    }
    // ---- stage B: 32 x 128 fp32 -> [n][k] bf16 hi/lo (4x4 transpose), swizzled
    {
      float4 row0 = *(const float4*)(Bm + (size_t)(k0 + kbB + 0) * Nn + n0 + nbB);
      float4 row1 = *(const float4*)(Bm + (size_t)(k0 + kbB + 1) * Nn + n0 + nbB);
      float4 row2 = *(const float4*)(Bm + (size_t)(k0 + kbB + 2) * Nn + n0 + nbB);
      float4 row3 = *(const float4*)(Bm + (size_t)(k0 + kbB + 3) * Nn + n0 + nbB);
      const float cols[4][4] = {{row0.x, row1.x, row2.x, row3.x},
                                {row0.y, row1.y, row2.y, row3.y},
                                {row0.z, row1.z, row2.z, row3.z},
                                {row0.w, row1.w, row2.w, row3.w}};
      #pragma unroll
      for (int nc = 0; nc < 4; nc++) {
        const int n = nbB + nc;
        ushort4 hv, lv;
        bf16_split(cols[nc][0], hv.x, lv.x);
        bf16_split(cols[nc][1], hv.y, lv.y);
        bf16_split(cols[nc][2], hv.z, lv.z);
        bf16_split(cols[nc][3], hv.w, lv.w);
        const int off = n * 32 + (kbB ^ ((n & 3) << 3));
        *(ushort4*)&BsH[off] = hv;
        *(ushort4*)&BsL[off] = lv;
      }
    }
    __syncthreads();

    // ---- compute: one MFMA k-step of 32 per tile
    short8_t aH[4], aL[4], bH[4], bL[4];
    #pragma unroll
    for (int i = 0; i < 4; i++) {
      const int row = wr * 64 + i * 16 + la;
      const int off = row * 32 + ((lb * 8) ^ ((row & 3) << 3));
      aH[i] = *(const short8_t*)&AsH[off];
      aL[i] = *(const short8_t*)&AsL[off];
    }
    #pragma unroll
    for (int j = 0; j < 4; j++) {
      const int row = wc * 64 + j * 16 + la;
      const int off = row * 32 + ((lb * 8) ^ ((row & 3) << 3));
      bH[j] = *(const short8_t*)&BsH[off];
      bL[j] = *(const short8_t*)&BsL[off];
    }
    #pragma unroll
    for (int i = 0; i < 4; i++)
      #pragma unroll
      for (int j = 0; j < 4; j++) {
        acc[i][j] = __builtin_amdgcn_mfma_f32_16x16x32_bf16(aH[i], bH[j], acc[i][j], 0, 0, 0);
        acc[i][j] = __builtin_amdgcn_mfma_f32_16x16x32_bf16(aH[i], bL[j], acc[i][j], 0, 0, 0);
        acc[i][j] = __builtin_amdgcn_mfma_f32_16x16x32_bf16(aL[i], bH[j], acc[i][j], 0, 0, 0);
      }
    __syncthreads();
  }

  // ---- epilogue: C/D layout col = la, row = lb*4 + r per 16x16 fragment
  const int colBase = n0 + wc * 64 + la;
  float biasv[4] = {0.f, 0.f, 0.f, 0.f};
  if (EPI >= 1) {
    #pragma unroll
    for (int j = 0; j < 4; j++) biasv[j] = bias[colBase + j * 16];
  }
  #pragma unroll
  for (int i = 0; i < 4; i++) {
    #pragma unroll
    for (int r = 0; r < 4; r++) {
      const int row = m0 + wr * 64 + i * 16 + lb * 4 + r;
      float* crow = Cm + (size_t)row * Nn;
      const float* rrow = (EPI == 2) ? (res + (size_t)row * Nn) : nullptr;
      #pragma unroll
      for (int j = 0; j < 4; j++) {
        float o = acc[i][j][r] + biasv[j];
        if (EPI == 2) o += rrow[colBase + j * 16];
        if (EPI == 3) o = gelu_exact(o);
        crow[colBase + j * 16] = o;
      }
    }
  }
}

// ---------------------------------------------------------------------------
// Fused attention (unchanged).
// ---------------------------------------------------------------------------
__global__ __launch_bounds__(256) void attn_kernel(
    const float* __restrict__ qkv, const int* __restrict__ nns,
    const float* __restrict__ xyz, const float* __restrict__ w_d1,
    const float* __restrict__ b_d1, const float* __restrict__ w_d2,
    const float* __restrict__ b_d2, float* __restrict__ out) {
  __shared__ __align__(16) float s_lds[8][4][256];
  __shared__ __align__(16) float ov_lds[8][256];
  __shared__ float a_lds[8][64];

  const int t = threadIdx.x;
  const int w = t >> 6;
  const int l = t & 63;
  const int h = l >> 4;
  const int c0 = l * 4;
  const int blk = blockIdx.x;

  const float4 w10 = *(const float4*)(w_d1 + c0);
  const float4 w11 = *(const float4*)(w_d1 + 256 + c0);
  const float4 b1v = *(const float4*)(b_d1 + c0);
  const float4 b2v = *(const float4*)(b_d2 + c0);

  for (int pl = 0; pl < 2; pl++) {
    const int p  = w * 2 + pl;
    const int gp = blk * 8 + p;
    const int b  = gp >> 13;

    const float4 q4 = *(const float4*)(qkv + (size_t)gp * 768 + c0);
    const float2 xy0 = *(const float2*)(xyz + gp * 2);

    int rowj[KNN];
    #pragma unroll
    for (int j = 0; j < KNN; j++) rowj[j] = (b << 13) + nns[gp * NNCOL + j];

    float myscore = 0.f;
    #pragma unroll
    for (int j = 0; j < KNN; j++) {
      const float4 k4 = *(const float4*)(qkv + (size_t)rowj[j] * 768 + 256 + c0);
      float d = q4.x * k4.x + q4.y * k4.y + q4.z * k4.z + q4.w * k4.w;
      d += __shfl_xor(d, 1); d += __shfl_xor(d, 2);
      d += __shfl_xor(d, 4); d += __shfl_xor(d, 8);
      if ((l & 15) == j) myscore = d;
    }
    myscore *= 0.125f;

    float mx = myscore;
    mx = fmaxf(mx, __shfl_xor(mx, 1)); mx = fmaxf(mx, __shfl_xor(mx, 2));
    mx = fmaxf(mx, __shfl_xor(mx, 4)); mx = fmaxf(mx, __shfl_xor(mx, 8));
    float e = __expf(myscore - mx);
    float sum = e;
    sum += __shfl_xor(sum, 1); sum += __shfl_xor(sum, 2);
    sum += __shfl_xor(sum, 4); sum += __shfl_xor(sum, 8);
    const float a = e / sum;
    a_lds[p][l] = a;
    __syncthreads();

    float sacc[4][4] = {};
    float4 ov = {0.f, 0.f, 0.f, 0.f};
    #pragma unroll
    for (int j = 0; j < KNN; j++) {
      const int r = rowj[j];
      const float4 v4 = *(const float4*)(qkv + (size_t)r * 768 + 512 + c0);
      const float2 xyj = *(const float2*)(xyz + r * 2);
      const float rx = xy0.x - xyj.x;
      const float ry = xy0.y - xyj.y;
      const float u0 = fmaxf(rx * w10.x + ry * w11.x + b1v.x, 0.f);
      const float u1 = fmaxf(rx * w10.y + ry * w11.y + b1v.y, 0.f);
      const float u2 = fmaxf(rx * w10.z + ry * w11.z + b1v.z, 0.f);
      const float u3 = fmaxf(rx * w10.w + ry * w11.w + b1v.w, 0.f);
      const float a0 = a_lds[p][0 * 16 + j];
      const float a1 = a_lds[p][1 * 16 + j];
      const float a2 = a_lds[p][2 * 16 + j];
      const float a3 = a_lds[p][3 * 16 + j];
      sacc[0][0] += a0 * u0; sacc[0][1] += a0 * u1; sacc[0][2] += a0 * u2; sacc[0][3] += a0 * u3;
      sacc[1][0] += a1 * u0; sacc[1][1] += a1 * u1; sacc[1][2] += a1 * u2; sacc[1][3] += a1 * u3;
      sacc[2][0] += a2 * u0; sacc[2][1] += a2 * u1; sacc[2][2] += a2 * u2; sacc[2][3] += a2 * u3;
      sacc[3][0] += a3 * u0; sacc[3][1] += a3 * u1; sacc[3][2] += a3 * u2; sacc[3][3] += a3 * u3;
      const float aown = (h < 2) ? (h == 0 ? a0 : a1) : (h == 2 ? a2 : a3);
      ov.x += aown * v4.x; ov.y += aown * v4.y;
      ov.z += aown * v4.z; ov.w += aown * v4.w;
    }
    #pragma unroll
    for (int hh = 0; hh < 4; hh++) {
      float4 sv;
      sv.x = sacc[hh][0]; sv.y = sacc[hh][1];
      sv.z = sacc[hh][2]; sv.w = sacc[hh][3];
      *(float4*)&s_lds[p][hh][c0] = sv;
    }
    float4 ovw;
    ovw.x = ov.x + b2v.x; ovw.y = ov.y + b2v.y;
    ovw.z = ov.z + b2v.z; ovw.w = ov.w + b2v.w;
    *(float4*)&ov_lds[p][c0] = ovw;
  }
  __syncthreads();

  const int d  = t;
  const int hh = d >> 6;
  float acc2[8];
  #pragma unroll
  for (int p = 0; p < 8; p++) acc2[p] = ov_lds[p][d];

  for (int c = 0; c < 256; c += 4) {
    const float wv0 = w_d2[(c + 0) * 256 + d];
    const float wv1 = w_d2[(c + 1) * 256 + d];
    const float wv2 = w_d2[(c + 2) * 256 + d];
    const float wv3 = w_d2[(c + 3) * 256 + d];
    #pragma unroll
    for (int p = 0; p < 8; p++) {
      const float4 s4 = *(const float4*)&s_lds[p][hh][c];
      acc2[p] += s4.x * wv0 + s4.y * wv1 + s4.z * wv2 + s4.w * wv3;
    }
  }
  const int gp0 = blk * 8;
  #pragma unroll
  for (int p = 0; p < 8; p++) out[(size_t)(gp0 + p) * 256 + d] = acc2[p];
}

// ---------------------------------------------------------------------------
// Launch
// ---------------------------------------------------------------------------
extern "C" void kernel_launch(void* const* d_in, const int* in_sizes, int n_in,
                              void* d_out, int out_size, void* d_ws,
                              size_t ws_size, hipStream_t stream) {
  const float* xyz      = (const float*)d_in[0];
  const float* xy_embed = (const float*)d_in[1];
  const int*   nns      = (const int*)d_in[2];
  const float* ln1_g    = (const float*)d_in[3];
  const float* ln1_b    = (const float*)d_in[4];
  const float* w_qkv    = (const float*)d_in[5];
  const float* w_d1     = (const float*)d_in[6];
  const float* b_d1     = (const float*)d_in[7];
  const float* w_d2     = (const float*)d_in[8];
  const float* b_d2     = (const float*)d_in[9];
  const float* w_proj   = (const float*)d_in[10];
  const float* b_proj   = (const float*)d_in[11];
  const float* ln2_g    = (const float*)d_in[12];
  const float* ln2_b    = (const float*)d_in[13];
  const float* w_m1     = (const float*)d_in[14];
  const float* b_m1     = (const float*)d_in[15];
  const float* w_m2     = (const float*)d_in[16];
  const float* b_m2     = (const float*)d_in[17];
  float* out = (float*)d_out;

  char* ws = (char*)d_ws;
  float* qkv     = (float*)ws;                              // BN*768*4  = 96 MB
  float* attnout = (float*)(ws + (size_t)BN * 768 * 4);     // BN*256*4  = 32 MB
  float* mid     = attnout;                                 // reused after proj
  float* st1     = (float*)(ws + (size_t)BN * 768 * 4 + (size_t)BN * 256 * 4);
  float* st2     = st1 + BN * 2;

  // 1. LN1 stats
  stats_kernel<<<BN / 4, 256, 0, stream>>>(xy_embed, st1);

  // 2. qkv = LN1(xy_embed) @ w_qkv
  gemm_mfma<1, 0><<<dim3(768 / 128, BN / 128), 256, 0, stream>>>(
      xy_embed, w_qkv, nullptr, qkv, nullptr, BN, 768, 256, st1, ln1_g, ln1_b);

  // 3. fused neighborhood attention (+pe restructure)
  attn_kernel<<<BN / 8, 256, 0, stream>>>(qkv, nns, xyz, w_d1, b_d1, w_d2,
                                          b_d2, attnout);

  // 4. x = xy_embed + attnout @ w_proj + b_proj   -> d_out
  gemm_mfma<0, 2><<<dim3(256 / 128, BN / 128), 256, 0, stream>>>(
      attnout, w_proj, b_proj, out, xy_embed, BN, 256, 256, nullptr, nullptr,
      nullptr);

  // 5. LN2 stats on x
  stats_kernel<<<BN / 4, 256, 0, stream>>>(out, st2);

  // 6/7. MLP, chunked over rows (mid reuses the attnout region, 32 MB)
  const int CHUNK = 8192;
  for (int ch = 0; ch < BN / CHUNK; ch++) {
    const float* xrow = out + (size_t)ch * CHUNK * 256;
    gemm_mfma<1, 3><<<dim3(1024 / 128, CHUNK / 128), 256, 0, stream>>>(
        xrow, w_m1, b_m1, mid, nullptr, CHUNK, 1024, 256,
        st2 + (size_t)ch * CHUNK * 2, ln2_g, ln2_b);
    gemm_mfma<0, 2><<<dim3(256 / 128, CHUNK / 128), 256, 0, stream>>>(
        mid, w_m2, b_m2, out + (size_t)ch * CHUNK * 256, xrow, CHUNK, 256,
        1024, nullptr, nullptr, nullptr);
  }
}

// Round 6
// 603.430 us; speedup vs baseline: 1.9626x; 1.5037x over previous
//
#include <hip/hip_runtime.h>
#include <hip/hip_bf16.h>
#include <math.h>

// Problem constants
#define NPTS 8192
#define BDIM 4
#define BN   32768   // BDIM*NPTS
#define CDIM 256
#define KNN  16
#define NNCOL 32

typedef __attribute__((ext_vector_type(8))) short short8_t;
typedef __attribute__((ext_vector_type(4))) float f32x4;

// ---------------------------------------------------------------------------
// bf16 helpers
// ---------------------------------------------------------------------------
__device__ __forceinline__ ushort bf16_rne(float f) {
  unsigned int u = __float_as_uint(f);
  u += 0x7fffu + ((u >> 16) & 1u);
  return (ushort)(u >> 16);
}
__device__ __forceinline__ void bf16_split(float f, ushort& h, ushort& l) {
  unsigned int u = __float_as_uint(f);
  h = (ushort)(u >> 16);
  float fh = __uint_as_float(u & 0xffff0000u);
  l = (ushort)(__float_as_uint(f - fh) >> 16);
}
__device__ __forceinline__ float bf16_tof(ushort h) {
  return __uint_as_float(((unsigned int)h) << 16);
}
__device__ __forceinline__ float gelu_exact(float z) {
  return 0.5f * z * (1.0f + erff(z * 0.70710678118654752f));
}

// ---------------------------------------------------------------------------
// Weight prep: transpose fp32 [R][Cc] -> hi/lo bf16 [Cc][R] (k-major for GEMM B)
// ---------------------------------------------------------------------------
__global__ __launch_bounds__(256) void wsplit_kernel(
    const float* __restrict__ in, ushort* __restrict__ oh,
    ushort* __restrict__ ol, int R, int Cc) {
  __shared__ float tile[32][33];
  const int tx = threadIdx.x & 31, ty = threadIdx.x >> 5;
  const int r0 = blockIdx.y * 32, c0 = blockIdx.x * 32;
  #pragma unroll
  for (int i = 0; i < 4; i++)
    tile[ty + 8 * i][tx] = in[(size_t)(r0 + ty + 8 * i) * Cc + c0 + tx];
  __syncthreads();
  #pragma unroll
  for (int i = 0; i < 4; i++) {
    const int cc = ty + 8 * i;
    ushort h, l;
    bf16_split(tile[tx][cc], h, l);
    oh[(size_t)(c0 + cc) * R + r0 + tx] = h;
    ol[(size_t)(c0 + cc) * R + r0 + tx] = l;
  }
}

// ---------------------------------------------------------------------------
// Fused LN stats + apply: x fp32 [rows][256] -> pre-split hi/lo bf16 of LN(x).
// One wave per row, 4 rows per block.
// ---------------------------------------------------------------------------
__global__ __launch_bounds__(256) void ln_apply_kernel(
    const float* __restrict__ x, const float* __restrict__ g,
    const float* __restrict__ b, ushort* __restrict__ oh,
    ushort* __restrict__ ol) {
  const int row = blockIdx.x * 4 + (threadIdx.x >> 6);
  const int l = threadIdx.x & 63;
  const float4 v = *(const float4*)(x + (size_t)row * CDIM + l * 4);
  float s  = v.x + v.y + v.z + v.w;
  float sq = v.x * v.x + v.y * v.y + v.z * v.z + v.w * v.w;
  #pragma unroll
  for (int off = 1; off < 64; off <<= 1) {
    s  += __shfl_xor(s, off);
    sq += __shfl_xor(sq, off);
  }
  const float m = s * (1.0f / 256.0f);
  const float r = rsqrtf(sq * (1.0f / 256.0f) - m * m + 1e-5f);
  const float4 gv = *(const float4*)(g + l * 4);
  const float4 bv = *(const float4*)(b + l * 4);
  const float y0 = (v.x - m) * r * gv.x + bv.x;
  const float y1 = (v.y - m) * r * gv.y + bv.y;
  const float y2 = (v.z - m) * r * gv.z + bv.z;
  const float y3 = (v.w - m) * r * gv.w + bv.w;
  ushort4 hv, lv;
  bf16_split(y0, hv.x, lv.x); bf16_split(y1, hv.y, lv.y);
  bf16_split(y2, hv.z, lv.z); bf16_split(y3, hv.w, lv.w);
  *(ushort4*)(oh + (size_t)row * CDIM + l * 4) = hv;
  *(ushort4*)(ol + (size_t)row * CDIM + l * 4) = lv;
}

// ---------------------------------------------------------------------------
// MFMA bf16x3 GEMM, pre-split operands.
//   A: hi/lo bf16 [M][K] row-major.  B: hi/lo bf16 [Nn][K] (k-major).
//   EPI 0: store bf16(acc) to CH [M][Nn]            (qkv)
//   EPI 2: store fp32 acc + bias + res to Cf        (proj / mlp2)
//   EPI 3: store split(gelu(acc + bias)) to CH/CL   (mlp1)
// Tile 128x128, BK=32, 256 threads = 4 waves (2x2), each wave 64x64 via
// 4x4 fragments of v_mfma_f32_16x16x32_bf16. LDS 32 KiB.
// Swizzle (verified round 3): ushort_off ^= (row&3)<<3.
// ---------------------------------------------------------------------------
template <int EPI>
__global__ __launch_bounds__(256) void gemm_bf3(
    const ushort* __restrict__ AH, const ushort* __restrict__ AL,
    const ushort* __restrict__ BH, const ushort* __restrict__ BL,
    const float* __restrict__ bias, float* __restrict__ Cf,
    ushort* __restrict__ CH, ushort* __restrict__ CL,
    const float* __restrict__ res, int M, int Nn, int Kk) {
  __shared__ __align__(16) ushort AsH[128 * 32];
  __shared__ __align__(16) ushort AsL[128 * 32];
  __shared__ __align__(16) ushort BsH[128 * 32];
  __shared__ __align__(16) ushort BsL[128 * 32];

  const int t = threadIdx.x;
  const int w = t >> 6;
  const int l = t & 63;
  const int la = l & 15;
  const int lb = l >> 4;
  const int wr = w >> 1;
  const int wc = w & 1;
  const int m0 = blockIdx.y * 128;
  const int n0 = blockIdx.x * 128;

  f32x4 acc[4][4];
  #pragma unroll
  for (int i = 0; i < 4; i++)
    #pragma unroll
    for (int j = 0; j < 4; j++) acc[i][j] = (f32x4){0.f, 0.f, 0.f, 0.f};

  for (int k0 = 0; k0 < Kk; k0 += 32) {
    // stage: granule g handles row g>>2, k-octet (g&3)*8; thread does g=t, t+256
    #pragma unroll
    for (int gi = 0; gi < 2; gi++) {
      const int g = t + gi * 256;
      const int row = g >> 2;
      const int kg = (g & 3) * 8;
      const int lds_off = row * 32 + (kg ^ ((row & 3) << 3));
      const size_t ga = (size_t)(m0 + row) * Kk + k0 + kg;
      const size_t gb = (size_t)(n0 + row) * Kk + k0 + kg;
      *(short8_t*)&AsH[lds_off] = *(const short8_t*)(AH + ga);
      *(short8_t*)&AsL[lds_off] = *(const short8_t*)(AL + ga);
      *(short8_t*)&BsH[lds_off] = *(const short8_t*)(BH + gb);
      *(short8_t*)&BsL[lds_off] = *(const short8_t*)(BL + gb);
    }
    __syncthreads();

    short8_t aH[4], aL[4], bH[4], bL[4];
    #pragma unroll
    for (int i = 0; i < 4; i++) {
      const int row = wr * 64 + i * 16 + la;
      const int off = row * 32 + ((lb * 8) ^ ((row & 3) << 3));
      aH[i] = *(const short8_t*)&AsH[off];
      aL[i] = *(const short8_t*)&AsL[off];
    }
    #pragma unroll
    for (int j = 0; j < 4; j++) {
      const int row = wc * 64 + j * 16 + la;
      const int off = row * 32 + ((lb * 8) ^ ((row & 3) << 3));
      bH[j] = *(const short8_t*)&BsH[off];
      bL[j] = *(const short8_t*)&BsL[off];
    }
    #pragma unroll
    for (int i = 0; i < 4; i++)
      #pragma unroll
      for (int j = 0; j < 4; j++) {
        acc[i][j] = __builtin_amdgcn_mfma_f32_16x16x32_bf16(aH[i], bH[j], acc[i][j], 0, 0, 0);
        acc[i][j] = __builtin_amdgcn_mfma_f32_16x16x32_bf16(aH[i], bL[j], acc[i][j], 0, 0, 0);
        acc[i][j] = __builtin_amdgcn_mfma_f32_16x16x32_bf16(aL[i], bH[j], acc[i][j], 0, 0, 0);
      }
    __syncthreads();
  }

  // epilogue: C/D layout col = la, row = lb*4 + r per 16x16 fragment
  const int colBase = n0 + wc * 64 + la;
  float biasv[4] = {0.f, 0.f, 0.f, 0.f};
  if (EPI >= 2) {
    #pragma unroll
    for (int j = 0; j < 4; j++) biasv[j] = bias[colBase + j * 16];
  }
  #pragma unroll
  for (int i = 0; i < 4; i++) {
    #pragma unroll
    for (int r = 0; r < 4; r++) {
      const int row = m0 + wr * 64 + i * 16 + lb * 4 + r;
      #pragma unroll
      for (int j = 0; j < 4; j++) {
        const int col = colBase + j * 16;
        float o = acc[i][j][r] + biasv[j];
        if (EPI == 0) {
          CH[(size_t)row * Nn + col] = bf16_rne(o);
        } else if (EPI == 2) {
          o += res[(size_t)row * Nn + col];
          Cf[(size_t)row * Nn + col] = o;
        } else {  // EPI == 3
          o = gelu_exact(o);
          ushort h, lo2;
          bf16_split(o, h, lo2);
          CH[(size_t)row * Nn + col] = h;
          CL[(size_t)row * Nn + col] = lo2;
        }
      }
    }
  }
}

// ---------------------------------------------------------------------------
// Fused attention: qkv table is bf16 [BN][768]. Structure as round 3, but
// gathers load ushort4 (8 B/lane) and the output is written pre-split hi/lo.
// ---------------------------------------------------------------------------
__global__ __launch_bounds__(256) void attn_kernel(
    const ushort* __restrict__ qkv, const int* __restrict__ nns,
    const float* __restrict__ xyz, const float* __restrict__ w_d1,
    const float* __restrict__ b_d1, const float* __restrict__ w_d2,
    const float* __restrict__ b_d2, ushort* __restrict__ outH,
    ushort* __restrict__ outL) {
  __shared__ __align__(16) float s_lds[8][4][256];
  __shared__ __align__(16) float ov_lds[8][256];
  __shared__ float a_lds[8][64];

  const int t = threadIdx.x;
  const int w = t >> 6;
  const int l = t & 63;
  const int h = l >> 4;
  const int c0 = l * 4;
  const int blk = blockIdx.x;

  const float4 w10 = *(const float4*)(w_d1 + c0);
  const float4 w11 = *(const float4*)(w_d1 + 256 + c0);
  const float4 b1v = *(const float4*)(b_d1 + c0);
  const float4 b2v = *(const float4*)(b_d2 + c0);

  for (int pl = 0; pl < 2; pl++) {
    const int p  = w * 2 + pl;
    const int gp = blk * 8 + p;
    const int b  = gp >> 13;

    const ushort4 qu = *(const ushort4*)(qkv + (size_t)gp * 768 + c0);
    const float q0 = bf16_tof(qu.x), q1 = bf16_tof(qu.y);
    const float q2 = bf16_tof(qu.z), q3 = bf16_tof(qu.w);
    const float2 xy0 = *(const float2*)(xyz + gp * 2);

    int rowj[KNN];
    #pragma unroll
    for (int j = 0; j < KNN; j++) rowj[j] = (b << 13) + nns[gp * NNCOL + j];

    float myscore = 0.f;
    #pragma unroll
    for (int j = 0; j < KNN; j++) {
      const ushort4 ku = *(const ushort4*)(qkv + (size_t)rowj[j] * 768 + 256 + c0);
      float d = q0 * bf16_tof(ku.x) + q1 * bf16_tof(ku.y) +
                q2 * bf16_tof(ku.z) + q3 * bf16_tof(ku.w);
      d += __shfl_xor(d, 1); d += __shfl_xor(d, 2);
      d += __shfl_xor(d, 4); d += __shfl_xor(d, 8);
      if ((l & 15) == j) myscore = d;
    }
    myscore *= 0.125f;

    float mx = myscore;
    mx = fmaxf(mx, __shfl_xor(mx, 1)); mx = fmaxf(mx, __shfl_xor(mx, 2));
    mx = fmaxf(mx, __shfl_xor(mx, 4)); mx = fmaxf(mx, __shfl_xor(mx, 8));
    float e = __expf(myscore - mx);
    float sum = e;
    sum += __shfl_xor(sum, 1); sum += __shfl_xor(sum, 2);
    sum += __shfl_xor(sum, 4); sum += __shfl_xor(sum, 8);
    const float a = e / sum;
    a_lds[p][l] = a;
    __syncthreads();

    float sacc[4][4] = {};
    float4 ov = {0.f, 0.f, 0.f, 0.f};
    #pragma unroll
    for (int j = 0; j < KNN; j++) {
      const int r = rowj[j];
      const ushort4 vu = *(const ushort4*)(qkv + (size_t)r * 768 + 512 + c0);
      const float v0 = bf16_tof(vu.x), v1 = bf16_tof(vu.y);
      const float v2 = bf16_tof(vu.z), v3 = bf16_tof(vu.w);
      const float2 xyj = *(const float2*)(xyz + r * 2);
      const float rx = xy0.x - xyj.x;
      const float ry = xy0.y - xyj.y;
      const float u0 = fmaxf(rx * w10.x + ry * w11.x + b1v.x, 0.f);
      const float u1 = fmaxf(rx * w10.y + ry * w11.y + b1v.y, 0.f);
      const float u2 = fmaxf(rx * w10.z + ry * w11.z + b1v.z, 0.f);
      const float u3 = fmaxf(rx * w10.w + ry * w11.w + b1v.w, 0.f);
      const float a0 = a_lds[p][0 * 16 + j];
      const float a1 = a_lds[p][1 * 16 + j];
      const float a2 = a_lds[p][2 * 16 + j];
      const float a3 = a_lds[p][3 * 16 + j];
      sacc[0][0] += a0 * u0; sacc[0][1] += a0 * u1; sacc[0][2] += a0 * u2; sacc[0][3] += a0 * u3;
      sacc[1][0] += a1 * u0; sacc[1][1] += a1 * u1; sacc[1][2] += a1 * u2; sacc[1][3] += a1 * u3;
      sacc[2][0] += a2 * u0; sacc[2][1] += a2 * u1; sacc[2][2] += a2 * u2; sacc[2][3] += a2 * u3;
      sacc[3][0] += a3 * u0; sacc[3][1] += a3 * u1; sacc[3][2] += a3 * u2; sacc[3][3] += a3 * u3;
      const float aown = (h < 2) ? (h == 0 ? a0 : a1) : (h == 2 ? a2 : a3);
      ov.x += aown * v0; ov.y += aown * v1;
      ov.z += aown * v2; ov.w += aown * v3;
    }
    #pragma unroll
    for (int hh = 0; hh < 4; hh++) {
      float4 sv;
      sv.x = sacc[hh][0]; sv.y = sacc[hh][1];
      sv.z = sacc[hh][2]; sv.w = sacc[hh][3];
      *(float4*)&s_lds[p][hh][c0] = sv;
    }
    float4 ovw;
    ovw.x = ov.x + b2v.x; ovw.y = ov.y + b2v.y;
    ovw.z = ov.z + b2v.z; ovw.w = ov.w + b2v.w;
    *(float4*)&ov_lds[p][c0] = ovw;
  }
  __syncthreads();

  const int d  = t;
  const int hh = d >> 6;
  float acc2[8];
  #pragma unroll
  for (int p = 0; p < 8; p++) acc2[p] = ov_lds[p][d];

  for (int c = 0; c < 256; c += 4) {
    const float wv0 = w_d2[(c + 0) * 256 + d];
    const float wv1 = w_d2[(c + 1) * 256 + d];
    const float wv2 = w_d2[(c + 2) * 256 + d];
    const float wv3 = w_d2[(c + 3) * 256 + d];
    #pragma unroll
    for (int p = 0; p < 8; p++) {
      const float4 s4 = *(const float4*)&s_lds[p][hh][c];
      acc2[p] += s4.x * wv0 + s4.y * wv1 + s4.z * wv2 + s4.w * wv3;
    }
  }
  const int gp0 = blk * 8;
  #pragma unroll
  for (int p = 0; p < 8; p++) {
    ushort hv, lv;
    bf16_split(acc2[p], hv, lv);
    outH[(size_t)(gp0 + p) * 256 + d] = hv;
    outL[(size_t)(gp0 + p) * 256 + d] = lv;
  }
}

// ---------------------------------------------------------------------------
// Launch
// ---------------------------------------------------------------------------
extern "C" void kernel_launch(void* const* d_in, const int* in_sizes, int n_in,
                              void* d_out, int out_size, void* d_ws,
                              size_t ws_size, hipStream_t stream) {
  const float* xyz      = (const float*)d_in[0];
  const float* xy_embed = (const float*)d_in[1];
  const int*   nns      = (const int*)d_in[2];
  const float* ln1_g    = (const float*)d_in[3];
  const float* ln1_b    = (const float*)d_in[4];
  const float* w_qkv    = (const float*)d_in[5];
  const float* w_d1     = (const float*)d_in[6];
  const float* b_d1     = (const float*)d_in[7];
  const float* w_d2     = (const float*)d_in[8];
  const float* b_d2     = (const float*)d_in[9];
  const float* w_proj   = (const float*)d_in[10];
  const float* b_proj   = (const float*)d_in[11];
  const float* ln2_g    = (const float*)d_in[12];
  const float* ln2_b    = (const float*)d_in[13];
  const float* w_m1     = (const float*)d_in[14];
  const float* b_m1     = (const float*)d_in[15];
  const float* w_m2     = (const float*)d_in[16];
  const float* b_m2     = (const float*)d_in[17];
  float* out = (float*)d_out;

  char* ws = (char*)d_ws;
  const size_t MB = 1024 * 1024;
  ushort* qkv_bf = (ushort*)(ws);              // 48 MB  [BN][768] bf16
  ushort* midH   = (ushort*)(ws);              // 32 MB  (overlays qkv, dead by MLP)
  ushort* midL   = (ushort*)(ws + 32 * MB);    // 32 MB  (overlays qkv+attnH)
  ushort* attnH  = (ushort*)(ws + 48 * MB);    // 16 MB
  ushort* attnL  = (ushort*)(ws + 64 * MB);    // 16 MB
  ushort* lnH    = (ushort*)(ws + 80 * MB);    // 16 MB
  ushort* lnL    = (ushort*)(ws + 96 * MB);    // 16 MB
  ushort* wbase  = (ushort*)(ws + 112 * MB);   // ~3 MB weights
  ushort* WqH  = wbase;            ushort* WqL  = WqH + 768 * 256;
  ushort* WpH  = WqL + 768 * 256;  ushort* WpL  = WpH + 256 * 256;
  ushort* Wm1H = WpL + 256 * 256;  ushort* Wm1L = Wm1H + 1024 * 256;
  ushort* Wm2H = Wm1L + 1024 * 256; ushort* Wm2L = Wm2H + 256 * 1024;

  // 0. weight transpose + split (k-major hi/lo bf16)
  wsplit_kernel<<<dim3(768 / 32, 256 / 32), 256, 0, stream>>>(w_qkv, WqH, WqL, 256, 768);
  wsplit_kernel<<<dim3(256 / 32, 256 / 32), 256, 0, stream>>>(w_proj, WpH, WpL, 256, 256);
  wsplit_kernel<<<dim3(1024 / 32, 256 / 32), 256, 0, stream>>>(w_m1, Wm1H, Wm1L, 256, 1024);
  wsplit_kernel<<<dim3(256 / 32, 1024 / 32), 256, 0, stream>>>(w_m2, Wm2H, Wm2L, 1024, 256);

  // 1. LN1 fused stats+apply -> pre-split A
  ln_apply_kernel<<<BN / 4, 256, 0, stream>>>(xy_embed, ln1_g, ln1_b, lnH, lnL);

  // 2. qkv = LN1(x) @ w_qkv -> bf16 table
  gemm_bf3<0><<<dim3(768 / 128, BN / 128), 256, 0, stream>>>(
      lnH, lnL, WqH, WqL, nullptr, nullptr, qkv_bf, nullptr, nullptr, BN, 768, 256);

  // 3. fused neighborhood attention -> pre-split attnout
  attn_kernel<<<BN / 8, 256, 0, stream>>>(qkv_bf, nns, xyz, w_d1, b_d1, w_d2,
                                          b_d2, attnH, attnL);

  // 4. x = xy_embed + attnout @ w_proj + b_proj -> d_out (fp32)
  gemm_bf3<2><<<dim3(256 / 128, BN / 128), 256, 0, stream>>>(
      attnH, attnL, WpH, WpL, b_proj, out, nullptr, nullptr, xy_embed, BN, 256, 256);

  // 5. LN2 fused stats+apply
  ln_apply_kernel<<<BN / 4, 256, 0, stream>>>(out, ln2_g, ln2_b, lnH, lnL);

  // 6/7. MLP, chunked (mid overlays qkv region, dead by now)
  const int CHUNK = 16384;
  for (int ch = 0; ch < BN / CHUNK; ch++) {
    float* xrow = out + (size_t)ch * CHUNK * 256;
    gemm_bf3<3><<<dim3(1024 / 128, CHUNK / 128), 256, 0, stream>>>(
        lnH + (size_t)ch * CHUNK * 256, lnL + (size_t)ch * CHUNK * 256,
        Wm1H, Wm1L, b_m1, nullptr, midH, midL, nullptr, CHUNK, 1024, 256);
    gemm_bf3<2><<<dim3(256 / 128, CHUNK / 128), 256, 0, stream>>>(
        midH, midL, Wm2H, Wm2L, b_m2, xrow, nullptr, nullptr, xrow, CHUNK, 256, 1024);
  }
}